// Round 7
// baseline (313.885 us; speedup 1.0000x reference)
//
#include <hip/hip_runtime.h>
#include <math.h>

#define B_ 4
#define L_ 2048
#define D_ 1024
#define H_ 16
#define DH_ 64
#define QKV_N 3072

typedef unsigned short ushort_t;
typedef unsigned int uint_t;
using bf16x8 = __attribute__((ext_vector_type(8))) short;
using f32x4  = __attribute__((ext_vector_type(4))) float;

__device__ __forceinline__ ushort_t f2bf(float f) {
    union { float f; unsigned int u; } v; v.f = f;
    unsigned int u = v.u;
    unsigned int rnd = ((u >> 16) & 1u) + 0x7fffu;
    return (ushort_t)((u + rnd) >> 16);
}

__device__ __forceinline__ float bf2f(ushort_t u) {
    union { unsigned int u; float f; } v;
    v.u = ((unsigned int)u) << 16;
    return v.f;
}

__device__ __forceinline__ void glds16(const void* g, void* l) {
    __builtin_amdgcn_global_load_lds(
        (const __attribute__((address_space(1))) unsigned int*)g,
        (__attribute__((address_space(3))) unsigned int*)l, 16, 0, 0);
}

// ---------------------------------------------------------------------------
// prep: blockIdx.z<4 -> transpose weight z into bf16 [n][k]; z==4 -> cast x.
// ---------------------------------------------------------------------------
__global__ __launch_bounds__(256) void prep(const float* __restrict__ Wq,
                                            const float* __restrict__ Wk,
                                            const float* __restrict__ Wv,
                                            const float* __restrict__ Wo,
                                            const float* __restrict__ x,
                                            ushort_t* __restrict__ wcat,
                                            ushort_t* __restrict__ wto,
                                            ushort_t* __restrict__ xb) {
    const int t = threadIdx.x;
    if (blockIdx.z == 4) {
        const int bid = blockIdx.y * 16 + blockIdx.x;
        const int base = bid * 32768 + t * 4;
        #pragma unroll
        for (int it = 0; it < 32; ++it) {
            float4 v = *(const float4*)(x + base + it * 1024);
            ushort4 o;
            o.x = f2bf(v.x); o.y = f2bf(v.y); o.z = f2bf(v.z); o.w = f2bf(v.w);
            *(ushort4*)(xb + base + it * 1024) = o;
        }
        return;
    }
    __shared__ ushort_t tile[64][65];
    const int widx = blockIdx.z;
    const float* W = (widx == 0) ? Wq : (widx == 1) ? Wk : (widx == 2) ? Wv : Wo;
    ushort_t* dst = (widx < 3) ? (wcat + (size_t)widx * 1024 * 1024) : wto;
    const int j = t & 63, i0 = t >> 6;
    const int kbase = blockIdx.y * 64, nbase = blockIdx.x * 64;
    #pragma unroll
    for (int it = 0; it < 16; ++it) {
        int i = it * 4 + i0;
        tile[i][j] = f2bf(W[(size_t)(kbase + i) * 1024 + nbase + j]);
    }
    __syncthreads();
    #pragma unroll
    for (int it = 0; it < 16; ++it) {
        int nn = it * 4 + i0;
        dst[(size_t)(nbase + nn) * 1024 + kbase + j] = tile[j][nn];
    }
}

// ---------------------------------------------------------------------------
// bf16 MFMA GEMM, tile 128x128, BK=64. Wt is [n][k]. A-first operand order:
// C row=quad*4+reg, col=l15. LDS rows = 8 chunks of 16B, phys = logical ^
// (row&7). fuse=1: bf16 out = relu(acc) + bf16 resid.
// If vt != nullptr and this block's columns are in the V region (>=2048),
// the epilogue scatters directly into the permuted Vt layout
// (Vt[(b*16+h)*64+d][tokgrp*64 + (tok&15)*4 + (tok>>4 & 3)]), eliminating
// the separate transv kernel.
// ---------------------------------------------------------------------------
__global__ __launch_bounds__(256) void gemm_mfma(const ushort_t* __restrict__ A,
                                                 const ushort_t* __restrict__ Wt,
                                                 ushort_t* __restrict__ Cbf,
                                                 const ushort_t* __restrict__ resid,
                                                 ushort_t* __restrict__ vt,
                                                 int M, int N, int K, int fuse) {
    __shared__ ushort_t As[128 * 64];
    __shared__ ushort_t Bs[128 * 64];
    const int t = threadIdx.x;
    const int w = t >> 6, ln = t & 63;
    const int l15 = ln & 15, quad = ln >> 4;
    const int bm = blockIdx.y * 128, bn = blockIdx.x * 128;
    const int wm = (w & 1) * 64, wn = (w >> 1) * 64;

    const ushort_t* Ap[4];
    const ushort_t* Bp[4];
    #pragma unroll
    for (int j = 0; j < 4; ++j) {
        const int i = t + j * 256;
        const int r = i >> 3;
        const int qg = (i & 7) ^ (r & 7);
        Ap[j] = A  + (size_t)(bm + r) * K + qg * 8;
        Bp[j] = Wt + (size_t)(bn + r) * K + qg * 8;
    }

    f32x4 acc[4][4] = {};

    for (int k0 = 0; k0 < K; k0 += 64) {
        __syncthreads();
        #pragma unroll
        for (int j = 0; j < 4; ++j) {
            glds16(Ap[j] + k0, &As[(t + j * 256) * 8]);
            glds16(Bp[j] + k0, &Bs[(t + j * 256) * 8]);
        }
        __syncthreads();

        #pragma unroll
        for (int kw = 0; kw < 2; ++kw) {
            bf16x8 af[4], bfr[4];
            #pragma unroll
            for (int im = 0; im < 4; ++im) {
                int row = wm + im * 16 + l15;
                int phys = (kw * 4 + quad) ^ (row & 7);
                af[im] = *(const bf16x8*)&As[row * 64 + phys * 8];
            }
            #pragma unroll
            for (int in = 0; in < 4; ++in) {
                int row = wn + in * 16 + l15;
                int phys = (kw * 4 + quad) ^ (row & 7);
                bfr[in] = *(const bf16x8*)&Bs[row * 64 + phys * 8];
            }
            #pragma unroll
            for (int im = 0; im < 4; ++im)
                #pragma unroll
                for (int in = 0; in < 4; ++in)
                    acc[im][in] = __builtin_amdgcn_mfma_f32_16x16x32_bf16(
                        af[im], bfr[in], acc[im][in], 0, 0, 0);
        }
    }

    if (vt && bn >= 2048) {
        // V-projection block: scatter into permuted Vt
        #pragma unroll
        for (int im = 0; im < 4; ++im) {
            #pragma unroll
            for (int in = 0; in < 4; ++in) {
                #pragma unroll
                for (int reg = 0; reg < 4; ++reg) {
                    int row = bm + wm + im * 16 + quad * 4 + reg;
                    int col = bn + wn + in * 16 + l15 - 2048;
                    int bb = row >> 11, tok = row & 2047;
                    int h = col >> 6, d = col & 63;
                    int tg = tok & 63;
                    int sc = (tg & 15) * 4 + (tg >> 4);
                    size_t addr = ((size_t)((bb * 16 + h) * 64 + d) << 11)
                                + (tok & ~63) + sc;
                    vt[addr] = f2bf(acc[im][in][reg]);
                }
            }
        }
    } else {
        #pragma unroll
        for (int im = 0; im < 4; ++im) {
            #pragma unroll
            for (int in = 0; in < 4; ++in) {
                #pragma unroll
                for (int reg = 0; reg < 4; ++reg) {
                    int row = bm + wm + im * 16 + quad * 4 + reg;
                    int col = bn + wn + in * 16 + l15;
                    size_t idx = (size_t)row * N + col;
                    float v = acc[im][in][reg];
                    if (fuse) v = fmaxf(v, 0.f) + bf2f(resid[idx]);
                    Cbf[idx] = f2bf(v);
                }
            }
        }
    }
}

// ---------------------------------------------------------------------------
// Flash attention, bf16 MFMA, static-max softmax. Block = 4 waves, 256
// queries (wave w owns 64: 4 m-tiles). 128-key K/V tiles, PV per 64-key
// phase through wave-private Ps. PV/l operands swapped: z-frag query=l15,
// d=quad*4+reg. Grid (64 bh, 8): Qt = 7 - blockIdx.y (LPT: longest first).
// ---------------------------------------------------------------------------
__global__ __launch_bounds__(256) void attn_mfma(const ushort_t* __restrict__ qkv,
                                                 const ushort_t* __restrict__ Vt,
                                                 ushort_t* __restrict__ Zb) {
    __shared__ ushort_t Ks[128 * 64];
    __shared__ ushort_t Vs[64 * 128];
    __shared__ ushort_t Ps[4][64 * 72];
    const int t = threadIdx.x, w = t >> 6, ln = t & 63;
    const int l15 = ln & 15, quad = ln >> 4;
    const int bh = blockIdx.x;
    const int b = bh >> 4, h = bh & 15;
    const int Qt = 7 - blockIdx.y;

    bf16x8 ones;
    #pragma unroll
    for (int i = 0; i < 8; ++i) ones[i] = (short)0x3f80;

    int kkey[4], kq[4], vd[4], vcq[4];
    #pragma unroll
    for (int j = 0; j < 4; ++j) {
        int i = t + j * 256;
        kkey[j] = i >> 3;
        kq[j]   = (i & 7) ^ (kkey[j] & 7);
        vd[j]   = i >> 4;
        int cqp = i & 15;
        vcq[j]  = (cqp & 8) | ((cqp & 7) ^ (vd[j] & 7));
    }
    const ushort_t* Kgb = qkv + 1024 + (size_t)b * L_ * QKV_N + h * DH_;
    const ushort_t* Vgb = Vt + (size_t)((b * H_ + h) * DH_) * L_;

    // Q fragments: rows Qt*256 + w*64 + mt*16 + l15
    bf16x8 qf[4][2];
    #pragma unroll
    for (int mt = 0; mt < 4; ++mt) {
        const ushort_t* qrow =
            qkv + (size_t)(b * L_ + Qt * 256 + w * 64 + mt * 16 + l15) * QKV_N + h * DH_;
        qf[mt][0] = *(const bf16x8*)(qrow + quad * 8);
        qf[mt][1] = *(const bf16x8*)(qrow + 32 + quad * 8);
    }

    f32x4 acc_o[4][4] = {};
    f32x4 l_acc[4] = {};

    const float c2 = 0.18033688f;   // 0.125 * log2(e)
    const int wq0 = Qt * 256 + w * 64;   // wave's first query row
    const int ktmax = 2 * Qt + 1;

    for (int kt = 0; kt <= ktmax; ++kt) {
        __syncthreads();
        #pragma unroll
        for (int j = 0; j < 4; ++j) {
            glds16(Kgb + (size_t)(kt * 128 + kkey[j]) * QKV_N + kq[j] * 8,
                   &Ks[(t + j * 256) * 8]);
            glds16(Vgb + (size_t)vd[j] * L_ + kt * 128 + vcq[j] * 8,
                   &Vs[(t + j * 256) * 8]);
        }
        __syncthreads();

        #pragma unroll
        for (int ph = 0; ph < 2; ++ph) {
            const int keylo = kt * 128 + ph * 64;
            if (keylo > wq0 + 63) continue;          // fully masked for wave
            const bool needMask = (keylo + 63 > wq0);

            // S + softmax per m-tile (streams acc_s, keeps VGPR low)
            #pragma unroll
            for (int mt = 0; mt < 4; ++mt) {
                f32x4 accs[4] = {};
                #pragma unroll
                for (int in = 0; in < 4; ++in) {
                    const int key = ph * 64 + in * 16 + l15;
                    #pragma unroll
                    for (int ks = 0; ks < 2; ++ks) {
                        int phys = (ks * 4 + quad) ^ (key & 7);
                        bf16x8 kf = *(const bf16x8*)&Ks[key * 64 + phys * 8];
                        accs[in] = __builtin_amdgcn_mfma_f32_16x16x32_bf16(
                            qf[mt][ks], kf, accs[in], 0, 0, 0);
                    }
                }
                #pragma unroll
                for (int reg = 0; reg < 4; ++reg) {
                    const int row = mt * 16 + quad * 4 + reg;
                    float pv[4];
                    #pragma unroll
                    for (int in = 0; in < 4; ++in) {
                        float s2 = fmaf(accs[in][reg], c2, -2.0f);
                        if (needMask) {
                            int col = keylo + in * 16 + l15;
                            int qg  = wq0 + row;
                            s2 = (col > qg) ? -100000.0f : s2;
                        }
                        pv[in] = __builtin_amdgcn_exp2f(s2);
                    }
                    uint_t u01 = __builtin_amdgcn_perm(
                        __float_as_uint(pv[1]), __float_as_uint(pv[0]), 0x07060302u);
                    uint_t u23 = __builtin_amdgcn_perm(
                        __float_as_uint(pv[3]), __float_as_uint(pv[2]), 0x07060302u);
                    uint2* dst = (uint2*)&Ps[w][row * 72 + l15 * 4];
                    *dst = make_uint2(u01, u23);
                }
            }

            // O += V^T-op @ P ; l += ones @ P   (same-wave LDS, no barrier)
            #pragma unroll
            for (int ks = 0; ks < 2; ++ks) {
                bf16x8 pf[4];
                #pragma unroll
                for (int mt = 0; mt < 4; ++mt)
                    pf[mt] = *(const bf16x8*)&Ps[w][(mt * 16 + l15) * 72 + ks * 32 + quad * 8];
                #pragma unroll
                for (int in = 0; in < 4; ++in) {
                    const int d = in * 16 + l15;
                    int physv = ph * 8 + (((ks * 4 + quad) ^ (d & 7)));
                    bf16x8 vf = *(const bf16x8*)&Vs[d * 128 + physv * 8];
                    #pragma unroll
                    for (int mt = 0; mt < 4; ++mt)
                        acc_o[mt][in] = __builtin_amdgcn_mfma_f32_16x16x32_bf16(
                            vf, pf[mt], acc_o[mt][in], 0, 0, 0);
                }
                #pragma unroll
                for (int mt = 0; mt < 4; ++mt)
                    l_acc[mt] = __builtin_amdgcn_mfma_f32_16x16x32_bf16(
                        ones, pf[mt], l_acc[mt], 0, 0, 0);
            }
        }
    }

    // epilogue: z-fragment query = l15, d = in*16 + quad*4 + reg
    #pragma unroll
    for (int mt = 0; mt < 4; ++mt) {
        const float inv = 1.0f / l_acc[mt][0];
        const int row = b * L_ + Qt * 256 + w * 64 + mt * 16 + l15;
        #pragma unroll
        for (int in = 0; in < 4; ++in) {
            const int dbase = h * DH_ + in * 16 + quad * 4;
            f32x4 a = acc_o[mt][in];
            ushort4 o;
            o.x = f2bf(a[0] * inv); o.y = f2bf(a[1] * inv);
            o.z = f2bf(a[2] * inv); o.w = f2bf(a[3] * inv);
            *(ushort4*)(Zb + (size_t)row * D_ + dbase) = o;
        }
    }
}

// ---------------------------------------------------------------------------
// LayerNorm over last dim (1024), bf16 input, fp32 out. One wave per row.
// ---------------------------------------------------------------------------
__global__ __launch_bounds__(64) void ln_kernel(const ushort_t* __restrict__ Y,
                                                const float* __restrict__ gamma,
                                                const float* __restrict__ beta,
                                                float* __restrict__ out) {
    const int row = blockIdx.x;
    const int t = threadIdx.x;
    const ushort_t* y = Y + (size_t)row * D_;

    float v[16];
    #pragma unroll
    for (int s = 0; s < 4; ++s) {
        ushort4 u = *(const ushort4*)(y + s * 256 + t * 4);
        v[s * 4 + 0] = bf2f(u.x);
        v[s * 4 + 1] = bf2f(u.y);
        v[s * 4 + 2] = bf2f(u.z);
        v[s * 4 + 3] = bf2f(u.w);
    }

    float sum = 0.f;
    #pragma unroll
    for (int i = 0; i < 16; ++i) sum += v[i];
    #pragma unroll
    for (int k = 1; k < 64; k <<= 1) sum += __shfl_xor(sum, k, 64);
    const float mu = sum * (1.f / (float)D_);

    float var = 0.f;
    #pragma unroll
    for (int i = 0; i < 16; ++i) {
        float d = v[i] - mu;
        var += d * d;
    }
    #pragma unroll
    for (int k = 1; k < 64; k <<= 1) var += __shfl_xor(var, k, 64);
    const float rstd = rsqrtf(var * (1.f / (float)D_) + 1e-12f);

    #pragma unroll
    for (int s = 0; s < 4; ++s) {
        const int col = s * 256 + t * 4;
        float4 g  = *(const float4*)(gamma + col);
        float4 bb = *(const float4*)(beta + col);
        float4 o;
        o.x = (v[s * 4 + 0] - mu) * rstd * g.x + bb.x;
        o.y = (v[s * 4 + 1] - mu) * rstd * g.y + bb.y;
        o.z = (v[s * 4 + 2] - mu) * rstd * g.z + bb.z;
        o.w = (v[s * 4 + 3] - mu) * rstd * g.w + bb.w;
        *(float4*)(out + (size_t)row * D_ + col) = o;
    }
}

// ---------------------------------------------------------------------------
extern "C" void kernel_launch(void* const* d_in, const int* in_sizes, int n_in,
                              void* d_out, int out_size, void* d_ws, size_t ws_size,
                              hipStream_t stream) {
    const float* x     = (const float*)d_in[0];
    const float* Wq    = (const float*)d_in[1];
    const float* Wk    = (const float*)d_in[2];
    const float* Wv    = (const float*)d_in[3];
    const float* Wo    = (const float*)d_in[4];
    const float* gamma = (const float*)d_in[5];
    const float* beta  = (const float*)d_in[6];
    float* out = (float*)d_out;

    char* ws = (char*)d_ws;
    ushort_t* x_bf = (ushort_t*)(ws);                 // 16 MB
    ushort_t* wcat = (ushort_t*)(ws + (16u  << 20));  //  6 MB (Wq^T|Wk^T|Wv^T)
    ushort_t* wto  = (ushort_t*)(ws + (22u  << 20));  //  2 MB
    ushort_t* qkv  = (ushort_t*)(ws + (24u  << 20));  // 48 MB [8192][3072] (V region unused)
    ushort_t* vt   = (ushort_t*)(ws + (72u  << 20));  // 16 MB
    ushort_t* z_bf = (ushort_t*)(ws + (88u  << 20));  // 16 MB
    ushort_t* y_bf = (ushort_t*)(ws + (104u << 20));  // 16 MB

    const int M = B_ * L_;

    prep<<<dim3(16, 16, 5), 256, 0, stream>>>(Wq, Wk, Wv, Wo, x, wcat, wto, x_bf);

    gemm_mfma<<<dim3(QKV_N / 128, M / 128), 256, 0, stream>>>(
        x_bf, wcat, qkv, nullptr, vt, M, QKV_N, D_, 0);

    attn_mfma<<<dim3(B_ * H_, 8), 256, 0, stream>>>(qkv, vt, z_bf);

    gemm_mfma<<<dim3(D_ / 128, M / 128), 256, 0, stream>>>(
        z_bf, wto, y_bf, x_bf, nullptr, M, D_, D_, 1);

    ln_kernel<<<M, 64, 0, stream>>>(y_bf, gamma, beta, out);
}

// Round 8
// 279.483 us; speedup vs baseline: 1.1231x; 1.1231x over previous
//
#include <hip/hip_runtime.h>
#include <math.h>

#define B_ 4
#define L_ 2048
#define D_ 1024
#define H_ 16
#define DH_ 64
#define QKV_N 3072

typedef unsigned short ushort_t;
typedef unsigned int uint_t;
using bf16x8 = __attribute__((ext_vector_type(8))) short;
using f32x4  = __attribute__((ext_vector_type(4))) float;

__device__ __forceinline__ ushort_t f2bf(float f) {
    union { float f; unsigned int u; } v; v.f = f;
    unsigned int u = v.u;
    unsigned int rnd = ((u >> 16) & 1u) + 0x7fffu;
    return (ushort_t)((u + rnd) >> 16);
}

__device__ __forceinline__ float bf2f(ushort_t u) {
    union { unsigned int u; float f; } v;
    v.u = ((unsigned int)u) << 16;
    return v.f;
}

__device__ __forceinline__ void glds16(const void* g, void* l) {
    __builtin_amdgcn_global_load_lds(
        (const __attribute__((address_space(1))) unsigned int*)g,
        (__attribute__((address_space(3))) unsigned int*)l, 16, 0, 0);
}

// ---------------------------------------------------------------------------
// prep: blockIdx.z<4 -> transpose weight z into bf16 [n][k]; z==4 -> cast x.
// ---------------------------------------------------------------------------
__global__ __launch_bounds__(256) void prep(const float* __restrict__ Wq,
                                            const float* __restrict__ Wk,
                                            const float* __restrict__ Wv,
                                            const float* __restrict__ Wo,
                                            const float* __restrict__ x,
                                            ushort_t* __restrict__ wcat,
                                            ushort_t* __restrict__ wto,
                                            ushort_t* __restrict__ xb) {
    const int t = threadIdx.x;
    if (blockIdx.z == 4) {
        const int bid = blockIdx.y * 16 + blockIdx.x;
        const int base = bid * 32768 + t * 4;
        #pragma unroll
        for (int it = 0; it < 32; ++it) {
            float4 v = *(const float4*)(x + base + it * 1024);
            ushort4 o;
            o.x = f2bf(v.x); o.y = f2bf(v.y); o.z = f2bf(v.z); o.w = f2bf(v.w);
            *(ushort4*)(xb + base + it * 1024) = o;
        }
        return;
    }
    __shared__ ushort_t tile[64][65];
    const int widx = blockIdx.z;
    const float* W = (widx == 0) ? Wq : (widx == 1) ? Wk : (widx == 2) ? Wv : Wo;
    ushort_t* dst = (widx < 3) ? (wcat + (size_t)widx * 1024 * 1024) : wto;
    const int j = t & 63, i0 = t >> 6;
    const int kbase = blockIdx.y * 64, nbase = blockIdx.x * 64;
    #pragma unroll
    for (int it = 0; it < 16; ++it) {
        int i = it * 4 + i0;
        tile[i][j] = f2bf(W[(size_t)(kbase + i) * 1024 + nbase + j]);
    }
    __syncthreads();
    #pragma unroll
    for (int it = 0; it < 16; ++it) {
        int nn = it * 4 + i0;
        dst[(size_t)(nbase + nn) * 1024 + kbase + j] = tile[j][nn];
    }
}

// ---------------------------------------------------------------------------
// bf16 MFMA GEMM, tile 128x128, BK=64. Wt is [n][k]. A-first operand order:
// C row=quad*4+reg, col=l15. LDS rows = 8 chunks of 16B, phys = logical ^
// (row&7). fuse=1: bf16 out = relu(acc) + bf16 resid.
// If vt != nullptr and this block's columns are in the V region (>=2048),
// the epilogue scatters directly into the permuted Vt layout, eliminating
// the separate transv kernel.
// ---------------------------------------------------------------------------
__global__ __launch_bounds__(256) void gemm_mfma(const ushort_t* __restrict__ A,
                                                 const ushort_t* __restrict__ Wt,
                                                 ushort_t* __restrict__ Cbf,
                                                 const ushort_t* __restrict__ resid,
                                                 ushort_t* __restrict__ vt,
                                                 int M, int N, int K, int fuse) {
    __shared__ ushort_t As[128 * 64];
    __shared__ ushort_t Bs[128 * 64];
    const int t = threadIdx.x;
    const int w = t >> 6, ln = t & 63;
    const int l15 = ln & 15, quad = ln >> 4;
    const int bm = blockIdx.y * 128, bn = blockIdx.x * 128;
    const int wm = (w & 1) * 64, wn = (w >> 1) * 64;

    const ushort_t* Ap[4];
    const ushort_t* Bp[4];
    #pragma unroll
    for (int j = 0; j < 4; ++j) {
        const int i = t + j * 256;
        const int r = i >> 3;
        const int qg = (i & 7) ^ (r & 7);
        Ap[j] = A  + (size_t)(bm + r) * K + qg * 8;
        Bp[j] = Wt + (size_t)(bn + r) * K + qg * 8;
    }

    f32x4 acc[4][4] = {};

    for (int k0 = 0; k0 < K; k0 += 64) {
        __syncthreads();
        #pragma unroll
        for (int j = 0; j < 4; ++j) {
            glds16(Ap[j] + k0, &As[(t + j * 256) * 8]);
            glds16(Bp[j] + k0, &Bs[(t + j * 256) * 8]);
        }
        __syncthreads();

        #pragma unroll
        for (int kw = 0; kw < 2; ++kw) {
            bf16x8 af[4], bfr[4];
            #pragma unroll
            for (int im = 0; im < 4; ++im) {
                int row = wm + im * 16 + l15;
                int phys = (kw * 4 + quad) ^ (row & 7);
                af[im] = *(const bf16x8*)&As[row * 64 + phys * 8];
            }
            #pragma unroll
            for (int in = 0; in < 4; ++in) {
                int row = wn + in * 16 + l15;
                int phys = (kw * 4 + quad) ^ (row & 7);
                bfr[in] = *(const bf16x8*)&Bs[row * 64 + phys * 8];
            }
            #pragma unroll
            for (int im = 0; im < 4; ++im)
                #pragma unroll
                for (int in = 0; in < 4; ++in)
                    acc[im][in] = __builtin_amdgcn_mfma_f32_16x16x32_bf16(
                        af[im], bfr[in], acc[im][in], 0, 0, 0);
        }
    }

    if (vt && bn >= 2048) {
        #pragma unroll
        for (int im = 0; im < 4; ++im) {
            #pragma unroll
            for (int in = 0; in < 4; ++in) {
                #pragma unroll
                for (int reg = 0; reg < 4; ++reg) {
                    int row = bm + wm + im * 16 + quad * 4 + reg;
                    int col = bn + wn + in * 16 + l15 - 2048;
                    int bb = row >> 11, tok = row & 2047;
                    int h = col >> 6, d = col & 63;
                    int tg = tok & 63;
                    int sc = (tg & 15) * 4 + (tg >> 4);
                    size_t addr = ((size_t)((bb * 16 + h) * 64 + d) << 11)
                                + (tok & ~63) + sc;
                    vt[addr] = f2bf(acc[im][in][reg]);
                }
            }
        }
    } else {
        #pragma unroll
        for (int im = 0; im < 4; ++im) {
            #pragma unroll
            for (int in = 0; in < 4; ++in) {
                #pragma unroll
                for (int reg = 0; reg < 4; ++reg) {
                    int row = bm + wm + im * 16 + quad * 4 + reg;
                    int col = bn + wn + in * 16 + l15;
                    size_t idx = (size_t)row * N + col;
                    float v = acc[im][in][reg];
                    if (fuse) v = fmaxf(v, 0.f) + bf2f(resid[idx]);
                    Cbf[idx] = f2bf(v);
                }
            }
        }
    }
}

// ---------------------------------------------------------------------------
// Flash attention, bf16 MFMA, static-max softmax. Block = 4 waves, 128
// queries (wave w: 32). 128-key K/V tiles, PV in two 64-key phases reusing
// wave-private Ps. PV/l MFMA operands swapped: z-fragment query=l15,
// d=quad*4+reg => ushort4 stores. Grid (64 bh, 16): Qt = 15 - blockIdx.y
// (longest blocks dispatch first; 3 blocks/CU resident + queue => LPT).
// ---------------------------------------------------------------------------
__global__ __launch_bounds__(256) void attn_mfma(const ushort_t* __restrict__ qkv,
                                                 const ushort_t* __restrict__ Vt,
                                                 ushort_t* __restrict__ Zb) {
    __shared__ ushort_t Ks[128 * 64];
    __shared__ ushort_t Vs[64 * 128];
    __shared__ ushort_t Ps[4][32 * 72];
    const int t = threadIdx.x, w = t >> 6, ln = t & 63;
    const int l15 = ln & 15, quad = ln >> 4;
    const int bh = blockIdx.x;
    const int b = bh >> 4, h = bh & 15;
    const int Qt = 15 - blockIdx.y;

    bf16x8 ones;
    #pragma unroll
    for (int i = 0; i < 8; ++i) ones[i] = (short)0x3f80;

    int kkey[4], kq[4], vd[4], vcq[4];
    #pragma unroll
    for (int j = 0; j < 4; ++j) {
        int i = t + j * 256;
        kkey[j] = i >> 3;
        kq[j]   = (i & 7) ^ (kkey[j] & 7);
        vd[j]   = i >> 4;
        int cqp = i & 15;
        vcq[j]  = (cqp & 8) | ((cqp & 7) ^ (vd[j] & 7));
    }
    const ushort_t* Kgb = qkv + 1024 + (size_t)b * L_ * QKV_N + h * DH_;
    const ushort_t* Vgb = Vt + (size_t)((b * H_ + h) * DH_) * L_;

    bf16x8 qf[2][2];
    #pragma unroll
    for (int mt = 0; mt < 2; ++mt) {
        const ushort_t* qrow =
            qkv + (size_t)(b * L_ + Qt * 128 + w * 32 + mt * 16 + l15) * QKV_N + h * DH_;
        qf[mt][0] = *(const bf16x8*)(qrow + quad * 8);
        qf[mt][1] = *(const bf16x8*)(qrow + 32 + quad * 8);
    }

    f32x4 acc_o[2][4] = {};
    f32x4 l_acc[2] = {};

    const float c2 = 0.18033688f;   // 0.125 * log2(e)

    for (int kt = 0; kt <= Qt; ++kt) {
        __syncthreads();
        #pragma unroll
        for (int j = 0; j < 4; ++j) {
            glds16(Kgb + (size_t)(kt * 128 + kkey[j]) * QKV_N + kq[j] * 8,
                   &Ks[(t + j * 256) * 8]);
            glds16(Vgb + (size_t)vd[j] * L_ + kt * 128 + vcq[j] * 8,
                   &Vs[(t + j * 256) * 8]);
        }
        __syncthreads();

        const bool masked = (kt == Qt);

        #pragma unroll
        for (int ph = 0; ph < 2; ++ph) {
            if (masked && ph && w < 2) continue;

            f32x4 acc_s[2][4] = {};
            #pragma unroll
            for (int in = 0; in < 4; ++in) {
                const int key = ph * 64 + in * 16 + l15;
                #pragma unroll
                for (int ks = 0; ks < 2; ++ks) {
                    int phys = (ks * 4 + quad) ^ (key & 7);
                    bf16x8 kf = *(const bf16x8*)&Ks[key * 64 + phys * 8];
                    acc_s[0][in] = __builtin_amdgcn_mfma_f32_16x16x32_bf16(
                        qf[0][ks], kf, acc_s[0][in], 0, 0, 0);
                    acc_s[1][in] = __builtin_amdgcn_mfma_f32_16x16x32_bf16(
                        qf[1][ks], kf, acc_s[1][in], 0, 0, 0);
                }
            }

            #pragma unroll
            for (int mt = 0; mt < 2; ++mt) {
                #pragma unroll
                for (int reg = 0; reg < 4; ++reg) {
                    const int row = mt * 16 + quad * 4 + reg;
                    float pv[4];
                    #pragma unroll
                    for (int in = 0; in < 4; ++in) {
                        float s2 = fmaf(acc_s[mt][in][reg], c2, -2.0f);
                        if (masked) {
                            int col = kt * 128 + ph * 64 + in * 16 + l15;
                            int qg  = Qt * 128 + w * 32 + row;
                            s2 = (col > qg) ? -100000.0f : s2;
                        }
                        pv[in] = __builtin_amdgcn_exp2f(s2);
                    }
                    uint_t u01 = __builtin_amdgcn_perm(
                        __float_as_uint(pv[1]), __float_as_uint(pv[0]), 0x07060302u);
                    uint_t u23 = __builtin_amdgcn_perm(
                        __float_as_uint(pv[3]), __float_as_uint(pv[2]), 0x07060302u);
                    uint2* dst = (uint2*)&Ps[w][row * 72 + l15 * 4];
                    *dst = make_uint2(u01, u23);
                }
            }

            #pragma unroll
            for (int ks = 0; ks < 2; ++ks) {
                bf16x8 pf0 = *(const bf16x8*)&Ps[w][(l15) * 72 + ks * 32 + quad * 8];
                bf16x8 pf1 = *(const bf16x8*)&Ps[w][(16 + l15) * 72 + ks * 32 + quad * 8];
                #pragma unroll
                for (int in = 0; in < 4; ++in) {
                    const int d = in * 16 + l15;
                    int physv = ph * 8 + (((ks * 4 + quad) ^ (d & 7)));
                    bf16x8 vf = *(const bf16x8*)&Vs[d * 128 + physv * 8];
                    acc_o[0][in] = __builtin_amdgcn_mfma_f32_16x16x32_bf16(
                        vf, pf0, acc_o[0][in], 0, 0, 0);
                    acc_o[1][in] = __builtin_amdgcn_mfma_f32_16x16x32_bf16(
                        vf, pf1, acc_o[1][in], 0, 0, 0);
                }
                l_acc[0] = __builtin_amdgcn_mfma_f32_16x16x32_bf16(ones, pf0, l_acc[0], 0, 0, 0);
                l_acc[1] = __builtin_amdgcn_mfma_f32_16x16x32_bf16(ones, pf1, l_acc[1], 0, 0, 0);
            }
        }
    }

    #pragma unroll
    for (int mt = 0; mt < 2; ++mt) {
        const float inv = 1.0f / l_acc[mt][0];
        const int row = b * L_ + Qt * 128 + w * 32 + mt * 16 + l15;
        #pragma unroll
        for (int in = 0; in < 4; ++in) {
            const int dbase = h * DH_ + in * 16 + quad * 4;
            f32x4 a = acc_o[mt][in];
            ushort4 o;
            o.x = f2bf(a[0] * inv); o.y = f2bf(a[1] * inv);
            o.z = f2bf(a[2] * inv); o.w = f2bf(a[3] * inv);
            *(ushort4*)(Zb + (size_t)row * D_ + dbase) = o;
        }
    }
}

// ---------------------------------------------------------------------------
// LayerNorm over last dim (1024), bf16 input, fp32 out. One wave per row.
// ---------------------------------------------------------------------------
__global__ __launch_bounds__(64) void ln_kernel(const ushort_t* __restrict__ Y,
                                                const float* __restrict__ gamma,
                                                const float* __restrict__ beta,
                                                float* __restrict__ out) {
    const int row = blockIdx.x;
    const int t = threadIdx.x;
    const ushort_t* y = Y + (size_t)row * D_;

    float v[16];
    #pragma unroll
    for (int s = 0; s < 4; ++s) {
        ushort4 u = *(const ushort4*)(y + s * 256 + t * 4);
        v[s * 4 + 0] = bf2f(u.x);
        v[s * 4 + 1] = bf2f(u.y);
        v[s * 4 + 2] = bf2f(u.z);
        v[s * 4 + 3] = bf2f(u.w);
    }

    float sum = 0.f;
    #pragma unroll
    for (int i = 0; i < 16; ++i) sum += v[i];
    #pragma unroll
    for (int k = 1; k < 64; k <<= 1) sum += __shfl_xor(sum, k, 64);
    const float mu = sum * (1.f / (float)D_);

    float var = 0.f;
    #pragma unroll
    for (int i = 0; i < 16; ++i) {
        float d = v[i] - mu;
        var += d * d;
    }
    #pragma unroll
    for (int k = 1; k < 64; k <<= 1) var += __shfl_xor(var, k, 64);
    const float rstd = rsqrtf(var * (1.f / (float)D_) + 1e-12f);

    #pragma unroll
    for (int s = 0; s < 4; ++s) {
        const int col = s * 256 + t * 4;
        float4 g  = *(const float4*)(gamma + col);
        float4 bb = *(const float4*)(beta + col);
        float4 o;
        o.x = (v[s * 4 + 0] - mu) * rstd * g.x + bb.x;
        o.y = (v[s * 4 + 1] - mu) * rstd * g.y + bb.y;
        o.z = (v[s * 4 + 2] - mu) * rstd * g.z + bb.z;
        o.w = (v[s * 4 + 3] - mu) * rstd * g.w + bb.w;
        *(float4*)(out + (size_t)row * D_ + col) = o;
    }
}

// ---------------------------------------------------------------------------
extern "C" void kernel_launch(void* const* d_in, const int* in_sizes, int n_in,
                              void* d_out, int out_size, void* d_ws, size_t ws_size,
                              hipStream_t stream) {
    const float* x     = (const float*)d_in[0];
    const float* Wq    = (const float*)d_in[1];
    const float* Wk    = (const float*)d_in[2];
    const float* Wv    = (const float*)d_in[3];
    const float* Wo    = (const float*)d_in[4];
    const float* gamma = (const float*)d_in[5];
    const float* beta  = (const float*)d_in[6];
    float* out = (float*)d_out;

    char* ws = (char*)d_ws;
    ushort_t* x_bf = (ushort_t*)(ws);                 // 16 MB
    ushort_t* wcat = (ushort_t*)(ws + (16u  << 20));  //  6 MB (Wq^T|Wk^T|Wv^T)
    ushort_t* wto  = (ushort_t*)(ws + (22u  << 20));  //  2 MB
    ushort_t* qkv  = (ushort_t*)(ws + (24u  << 20));  // 48 MB [8192][3072] (V region unused)
    ushort_t* vt   = (ushort_t*)(ws + (72u  << 20));  // 16 MB
    ushort_t* z_bf = (ushort_t*)(ws + (88u  << 20));  // 16 MB
    ushort_t* y_bf = (ushort_t*)(ws + (104u << 20));  // 16 MB

    const int M = B_ * L_;

    prep<<<dim3(16, 16, 5), 256, 0, stream>>>(Wq, Wk, Wv, Wo, x, wcat, wto, x_bf);

    gemm_mfma<<<dim3(QKV_N / 128, M / 128), 256, 0, stream>>>(
        x_bf, wcat, qkv, nullptr, vt, M, QKV_N, D_, 0);

    attn_mfma<<<dim3(B_ * H_, 16), 256, 0, stream>>>(qkv, vt, z_bf);

    gemm_mfma<<<dim3(D_ / 128, M / 128), 256, 0, stream>>>(
        z_bf, wto, y_bf, x_bf, nullptr, M, D_, D_, 1);

    ln_kernel<<<M, 64, 0, stream>>>(y_bf, gamma, beta, out);
}